// Round 13
// baseline (504.863 us; speedup 1.0000x reference)
//
#include <hip/hip_runtime.h>

#define CAP_E 5120              // edge slots per 256-node bucket (mean ~4090, +16 sigma)
#define CAP_S (CAP_E + 256)     // srcs slots per bucket (edges + self loops)
#define DBLK  1024              // k_dense2 grid

typedef __attribute__((ext_vector_type(8))) short bf16x8;
typedef __attribute__((ext_vector_type(4))) float f32x4;

__device__ __forceinline__ float lrelu(float v, float s) { return v >= 0.f ? v : s * v; }

__device__ __forceinline__ short bf16t(float f) {
  return (short)(__float_as_uint(f) >> 16);
}
__device__ __forceinline__ unsigned short bf16rn(float f) {  // round-to-nearest-even
  unsigned u = __float_as_uint(f);
  return (unsigned short)((u + 0x7fffu + ((u >> 16) & 1u)) >> 16);
}
__device__ __forceinline__ unsigned pk2(float a, float b) {
  return (unsigned)bf16rn(a) | ((unsigned)bf16rn(b) << 16);
}

// --- detect whether edge_index arrived as int64 or int32 ---
__global__ void k_detect(const void* __restrict__ ei, int N, int* __restrict__ flag) {
  __shared__ int bad;
  if (threadIdx.x == 0) bad = 0;
  __syncthreads();
  const long long* p = (const long long*)ei;
  int my = 0;
  for (int i = threadIdx.x; i < 1024; i += blockDim.x) {
    long long v = p[i];
    if (v < 0 || v >= (long long)N) my = 1;
  }
  if (my) atomicExch(&bad, 1);
  __syncthreads();
  if (threadIdx.x == 0) *flag = bad ? 0 : 1;  // 1 => int64
}

// --- fc_W -> frag-order bf16 (32 KB), done once; consumed via L1 by k_dense2 ---
__global__ void k_wconv(const float* __restrict__ fcW, bf16x8* __restrict__ fcWf) {
  int idx = blockIdx.x * 256 + threadIdx.x;
  if (idx >= 2048) return;
  int tq = idx >> 6, l = idx & 63;
  int t = tq >> 2, q = tq & 3;
  int col = (l & 15) + t * 16;
  int kb = q * 32 + (l >> 4) * 8;
  const float* wr = fcW + col * 128 + kb;
  bf16x8 v;
#pragma unroll
  for (int i = 0; i < 8; ++i) v[i] = bf16t(wr[i]);
  fcWf[idx] = v;
}

// --- per-node packed 64B row: xebf[n] = {16 bf16 x, 8 f32 als}; ald separate ---
__global__ void k_alpha(const float* __restrict__ x, const float* __restrict__ Wc,
                        const float* __restrict__ a_src, const float* __restrict__ a_dst,
                        uint4* __restrict__ xebf, float* __restrict__ ald, int N) {
  __shared__ float vs[128], vd[128];
  for (int t = threadIdx.x; t < 256; t += blockDim.x) {
    int h = (t & 127) >> 4, d = t & 15;
    const float* wrow = Wc + h * 256 + d * 16;
    const float* av = (t < 128 ? a_src : a_dst) + h * 16;
    float s = 0.f;
#pragma unroll
    for (int f = 0; f < 16; ++f) s += wrow[f] * av[f];
    if (t < 128) vs[h * 16 + d] = s; else vd[h * 16 + d] = s;
  }
  __syncthreads();
  for (int n = blockIdx.x * blockDim.x + threadIdx.x; n < N; n += gridDim.x * blockDim.x) {
    float xv[16];
    const float4* xr = (const float4*)(x + (size_t)n * 16);
    float4 q0 = xr[0], q1 = xr[1], q2 = xr[2], q3 = xr[3];
    xv[0]=q0.x; xv[1]=q0.y; xv[2]=q0.z; xv[3]=q0.w;
    xv[4]=q1.x; xv[5]=q1.y; xv[6]=q1.z; xv[7]=q1.w;
    xv[8]=q2.x; xv[9]=q2.y; xv[10]=q2.z; xv[11]=q2.w;
    xv[12]=q3.x; xv[13]=q3.y; xv[14]=q3.z; xv[15]=q3.w;
    float rs[8], rd[8];
#pragma unroll
    for (int h = 0; h < 8; ++h) {
      float s1 = 0.f, s2 = 0.f;
#pragma unroll
      for (int d = 0; d < 16; ++d) { s1 += xv[d] * vs[h * 16 + d]; s2 += xv[d] * vd[h * 16 + d]; }
      rs[h] = s1; rd[h] = s2;
    }
    uint4* po = xebf + (size_t)n * 4;
    uint4 wa, wb;
    wa.x = pk2(xv[0], xv[1]);  wa.y = pk2(xv[2], xv[3]);
    wa.z = pk2(xv[4], xv[5]);  wa.w = pk2(xv[6], xv[7]);
    wb.x = pk2(xv[8], xv[9]);  wb.y = pk2(xv[10], xv[11]);
    wb.z = pk2(xv[12], xv[13]); wb.w = pk2(xv[14], xv[15]);
    po[0] = wa; po[1] = wb;
    po[2] = *(const uint4*)(&rs[0]);
    po[3] = *(const uint4*)(&rs[4]);
    float4* pd = (float4*)(ald + (size_t)n * 8);
    pd[0] = make_float4(rd[0], rd[1], rd[2], rd[3]);
    pd[1] = make_float4(rd[4], rd[5], rd[6], rd[7]);
  }
}

// --- partition edges into fixed-capacity bucket regions (bucket = dst>>8);
//     one global atomic per (block,bucket); pairs = (src<<8)|(dst&255). ---
__global__ __launch_bounds__(256) void k_bfill2(const void* __restrict__ ei,
                                                const int* __restrict__ flag,
                                                int* __restrict__ ecur,
                                                unsigned* __restrict__ pairs, int E) {
  __shared__ int hist[512];
  __shared__ int gbase[512];
  const int is64 = *flag;
  const int base = blockIdx.x * 8192;
  for (int i = threadIdx.x; i < 512; i += 256) hist[i] = 0;
  __syncthreads();
  unsigned pk[32];
  int bs[32];  // (bucket<<13)|slot, or -1 if invalid
#pragma unroll
  for (int k = 0; k < 32; ++k) {
    const int i = base + k * 256 + threadIdx.x;
    bs[k] = -1;
    if (i < E) {
      int s, d;
      if (is64) { s = (int)((const long long*)ei)[i]; d = (int)((const long long*)ei)[(size_t)E + i]; }
      else      { s = ((const int*)ei)[i];            d = ((const int*)ei)[(size_t)E + i]; }
      const int b = d >> 8;
      const int slot = atomicAdd(&hist[b], 1);
      pk[k] = ((unsigned)s << 8) | (unsigned)(d & 255);
      bs[k] = (b << 13) | slot;
    }
  }
  __syncthreads();
  for (int i = threadIdx.x; i < 512; i += 256)
    if (hist[i] > 0) gbase[i] = i * CAP_E + atomicAdd(&ecur[i], hist[i]);
  __syncthreads();
#pragma unroll
  for (int k = 0; k < 32; ++k) {
    if (bs[k] >= 0) {
      const int b = bs[k] >> 13, slot = bs[k] & 8191;
      const int gi = gbase[b] + slot;
      if (gi < (b + 1) * CAP_E) pairs[gi] = pk[k];   // capacity guard (never triggers)
    }
  }
}

// --- per-bucket CSR: LDS histogram + scan; writes off[n], deg[n], srcs ---
__global__ __launch_bounds__(256) void k_bcsr(const unsigned* __restrict__ pairs,
                                              const int* __restrict__ ecur,
                                              int* __restrict__ off, int* __restrict__ deg,
                                              int* __restrict__ srcs, int N) {
  __shared__ int cnt[256], cur[256], wtot[4];
  const int b = blockIdx.x, t = threadIdx.x;
  const int nbase = b << 8;
  const int ncount = min(256, N - nbase);
  const int ebeg = b * CAP_E;
  const int eend = ebeg + min(ecur[b], CAP_E);
  const int ob = b * CAP_S;
  cnt[t] = (t < ncount) ? 1 : 0;  // self loop
  __syncthreads();
  for (int i = ebeg + t; i < eend; i += 256) atomicAdd(&cnt[pairs[i] & 255], 1);
  __syncthreads();
  const int wid = t >> 6, lane = t & 63;
  const int v = cnt[t];
  int inc = v;
#pragma unroll
  for (int d = 1; d < 64; d <<= 1) {
    int u = __shfl_up(inc, d, 64);
    if (lane >= d) inc += u;
  }
  if (lane == 63) wtot[wid] = inc;
  __syncthreads();
  int wb = 0;
  for (int w = 0; w < wid; ++w) wb += wtot[w];
  const int exc = wb + inc - v;
  if (t < ncount) {
    off[nbase + t] = ob + exc;
    deg[nbase + t] = v;
    srcs[ob + exc] = nbase + t;   // self loop first
    cur[t] = exc + 1;
  }
  __syncthreads();
  for (int i = ebeg + t; i < eend; i += 256) {
    unsigned e = pairs[i];
    int slot = atomicAdd(&cur[e & 255], 1);
    srcs[ob + slot] = (int)(e >> 8);
  }
}

// --- gather-aggregate + W_conv apply -> xlocal[N,128]. One wave per node,
//     8 edges/iter (es=lane>>3, h=lane&7); packed 64B rows (bf16 x + f32 als);
//     cross-node software pipeline. (round-9 structure, off/deg CSR) ---
__global__ __launch_bounds__(256) void k_xlocal(
    const uint4* __restrict__ xebf, const int* __restrict__ off,
    const int* __restrict__ deg, const int* __restrict__ srcs,
    const float* __restrict__ ald,
    const float* __restrict__ Wc, const float* __restrict__ b_conv,
    float* __restrict__ xlocal, int N) {
  __shared__ float W2t[2048];     // [d][h*16+f]
  __shared__ float myx[4][128];
  __shared__ float dsh[4][8];
  for (int i = threadIdx.x; i < 2048; i += blockDim.x) {
    int h = i >> 8, d = (i >> 4) & 15, f = i & 15;
    W2t[d * 128 + h * 16 + f] = Wc[i];
  }
  __syncthreads();
  const int wid = threadIdx.x >> 6, lane = threadIdx.x & 63;
  const int es = lane >> 3, h = lane & 7;
  const int c0 = lane, c1 = lane + 64;
  const int h0 = lane >> 4, h1 = h0 + 4;
  const float bc0 = b_conv[c0], bc1 = b_conv[c1];
  const int gw = blockIdx.x * 4 + wid, nwv = gridDim.x * 4;
  if (gw >= N) return;
  // prologue: node gw's extent + strip-0 row
  int b0 = off[gw], e0 = b0 + deg[gw];
  int s0 = srcs[min(b0 + es, e0 - 1)];
  uint4 xa = xebf[(size_t)s0 * 4], xb = xebf[(size_t)s0 * 4 + 1];
  float av = ((const float*)(xebf + (size_t)s0 * 4))[8 + h];
  for (int n = gw; n < N; n += nwv) {
    const int nn = n + nwv;
    int b1 = 0, e1 = 1;
    if (nn < N) { b1 = off[nn]; e1 = b1 + deg[nn]; }   // issue early
    const float aldh = ald[(size_t)n * 8 + h];
    float acc[16];
#pragma unroll
    for (int d = 0; d < 16; ++d) acc[d] = 0.f;
    float den = 0.f;
    for (int base = b0; base < e0; base += 8) {
      // prefetch next strip (clamped; last iteration's prefetch is discarded)
      int sn = srcs[min(base + 8 + es, e0 - 1)];
      const uint4* rn = xebf + (size_t)sn * 4;
      uint4 na = rn[0], nb = rn[1];
      float avn = ((const float*)rn)[8 + h];
      // compute current strip (decode bf16 pairs on the fly)
      float e = av + aldh;
      float w = ((base + es) < e0) ? __expf(e >= 0.f ? e : 0.2f * e) : 0.f;
      den += w;
      acc[0]  += w * __uint_as_float(xa.x << 16);
      acc[1]  += w * __uint_as_float(xa.x & 0xFFFF0000u);
      acc[2]  += w * __uint_as_float(xa.y << 16);
      acc[3]  += w * __uint_as_float(xa.y & 0xFFFF0000u);
      acc[4]  += w * __uint_as_float(xa.z << 16);
      acc[5]  += w * __uint_as_float(xa.z & 0xFFFF0000u);
      acc[6]  += w * __uint_as_float(xa.w << 16);
      acc[7]  += w * __uint_as_float(xa.w & 0xFFFF0000u);
      acc[8]  += w * __uint_as_float(xb.x << 16);
      acc[9]  += w * __uint_as_float(xb.x & 0xFFFF0000u);
      acc[10] += w * __uint_as_float(xb.y << 16);
      acc[11] += w * __uint_as_float(xb.y & 0xFFFF0000u);
      acc[12] += w * __uint_as_float(xb.z << 16);
      acc[13] += w * __uint_as_float(xb.z & 0xFFFF0000u);
      acc[14] += w * __uint_as_float(xb.w << 16);
      acc[15] += w * __uint_as_float(xb.w & 0xFFFF0000u);
      xa = na; xb = nb; av = avn;
    }
    // issue next node's strip-0 srcs (b1 already arrived)
    if (nn < N) s0 = srcs[min(b1 + es, e1 - 1)];
    // reduce across the 8 edge-slots (lanes h, h+8, ..., h+56)
#pragma unroll
    for (int m = 8; m < 64; m <<= 1) {
#pragma unroll
      for (int d = 0; d < 16; ++d) acc[d] += __shfl_xor(acc[d], m, 64);
      den += __shfl_xor(den, m, 64);
    }
    if (es == 0) {
#pragma unroll
      for (int d = 0; d < 16; ++d) myx[wid][h * 16 + d] = acc[d];
      dsh[wid][h] = den;
    }
    // issue next node's strip-0 row loads (hide under matvec+store)
    if (nn < N) {
      const uint4* r = xebf + (size_t)s0 * 4;
      xa = r[0]; xb = r[1];
      av = ((const float*)r)[8 + h];
    }
    // x_local[c] = (W_h . acc_h)/den_h + b_conv[c]
    const float rd0 = 1.f / dsh[wid][h0];
    const float rd1 = 1.f / dsh[wid][h1];
    float xl0 = 0.f, xl1 = 0.f;
#pragma unroll
    for (int d = 0; d < 16; ++d) {
      xl0 += myx[wid][h0 * 16 + d] * W2t[d * 128 + c0];
      xl1 += myx[wid][h1 * 16 + d] * W2t[d * 128 + c1];
    }
    xlocal[(size_t)n * 128 + c0] = xl0 * rd0 + bc0;
    xlocal[(size_t)n * 128 + c1] = xl1 * rd1 + bc1;
    b0 = b1; e0 = e1;
  }
}

// --- dense chain via MFMA. One wave per 16-node tile. B-frags read from global
//     frag-order bf16 fc_W (32 KB, L1-resident); LDS = x-stage only -> 4 blocks/CU.
//     colsum via per-block partials (no atomics). ---
__global__ __launch_bounds__(256) void k_dense2(
    float* __restrict__ xlocal,   // in-place: rows read then overwritten
    const bf16x8* __restrict__ fcWf, const float* __restrict__ fcb,
    const float* __restrict__ lng, const float* __restrict__ lnb,
    float* __restrict__ colpart, int N) {
  __shared__ float xs[4][2112];   // per-wave 16x132 f32 stage (pad kills A-read conflicts)
  __shared__ float colred[4][128];
  const int wid = threadIdx.x >> 6, lane = threadIdx.x & 63;
  float* X = xs[wid];
  const int lg = lane >> 4;       // row-group (C) / k-group (A,B)
  const int lc = lane & 15;       // col-in-tile (C,B) / row (A)
  float fb[8], g[8], bb[8];
#pragma unroll
  for (int t = 0; t < 8; ++t) {
    int c = lc + t * 16;
    fb[t] = fcb[c]; g[t] = lng[c]; bb[t] = lnb[c];
  }
  float cs[8];
#pragma unroll
  for (int t = 0; t < 8; ++t) cs[t] = 0.f;
  const int ntiles = (N + 15) >> 4;
  const int srow = lane >> 2, sseg = lane & 3;
  for (int tile = blockIdx.x * 4 + wid; tile < ntiles; tile += gridDim.x * 4) {
    const int nb = tile * 16;
    // stage 16x128 tile of xlocal into LDS
#pragma unroll
    for (int j = 0; j < 8; ++j) {
      int n = min(nb + srow, N - 1);
      float4 v = *(const float4*)(xlocal + (size_t)n * 128 + (sseg + 4 * j) * 4);
      *(float4*)(X + srow * 132 + (sseg + 4 * j) * 4) = v;
    }
    // A fragments (hi/lo split), GEMM1
    bf16x8 Ah[4], Al[4];
#pragma unroll
    for (int q = 0; q < 4; ++q) {
      const float* p = X + lc * 132 + q * 32 + lg * 8;
      float a[8];
      *(float4*)(a) = *(const float4*)(p);
      *(float4*)(a + 4) = *(const float4*)(p + 4);
#pragma unroll
      for (int i = 0; i < 8; ++i) {
        unsigned u = __float_as_uint(a[i]);
        Ah[q][i] = (short)(u >> 16);
        Al[q][i] = bf16t(a[i] - __uint_as_float(u & 0xFFFF0000u));
      }
    }
    f32x4 acc[8];
#pragma unroll
    for (int t = 0; t < 8; ++t) acc[t] = (f32x4){0.f, 0.f, 0.f, 0.f};
#pragma unroll
    for (int t = 0; t < 8; ++t)
#pragma unroll
      for (int q = 0; q < 4; ++q) {
        bf16x8 b = fcWf[(t * 4 + q) * 64 + lane];
        acc[t] = __builtin_amdgcn_mfma_f32_16x16x32_bf16(Ah[q], b, acc[t], 0, 0, 0);
        acc[t] = __builtin_amdgcn_mfma_f32_16x16x32_bf16(Al[q], b, acc[t], 0, 0, 0);
      }
    // softmax over 128 cols per node-row; xl2 = lrelu(x*att, 0.2); write back to LDS
    float l1[8][4];
#pragma unroll
    for (int t = 0; t < 8; ++t)
#pragma unroll
      for (int r = 0; r < 4; ++r) {
        float z = acc[t][r] + fb[t];
        l1[t][r] = fmaxf(z, 0.01f * z);
      }
#pragma unroll
    for (int r = 0; r < 4; ++r) {
      float m = l1[0][r];
#pragma unroll
      for (int t = 1; t < 8; ++t) m = fmaxf(m, l1[t][r]);
#pragma unroll
      for (int msk = 1; msk < 16; msk <<= 1) m = fmaxf(m, __shfl_xor(m, msk, 64));
      float s = 0.f;
#pragma unroll
      for (int t = 0; t < 8; ++t) { l1[t][r] = __expf(l1[t][r] - m); s += l1[t][r]; }
#pragma unroll
      for (int msk = 1; msk < 16; msk <<= 1) s += __shfl_xor(s, msk, 64);
      float sinv = 1.f / s;
      const int row = lg * 4 + r;
#pragma unroll
      for (int t = 0; t < 8; ++t) {
        float xv = X[row * 132 + lc + 16 * t];
        float y = xv * (l1[t][r] * sinv);
        l1[t][r] = fmaxf(y, 0.2f * y);
      }
    }
#pragma unroll
    for (int t = 0; t < 8; ++t)
#pragma unroll
      for (int r = 0; r < 4; ++r)
        X[(lg * 4 + r) * 132 + lc + 16 * t] = l1[t][r];
    // GEMM2 on xl2
#pragma unroll
    for (int q = 0; q < 4; ++q) {
      const float* p = X + lc * 132 + q * 32 + lg * 8;
      float a[8];
      *(float4*)(a) = *(const float4*)(p);
      *(float4*)(a + 4) = *(const float4*)(p + 4);
#pragma unroll
      for (int i = 0; i < 8; ++i) {
        unsigned u = __float_as_uint(a[i]);
        Ah[q][i] = (short)(u >> 16);
        Al[q][i] = bf16t(a[i] - __uint_as_float(u & 0xFFFF0000u));
      }
    }
#pragma unroll
    for (int t = 0; t < 8; ++t) acc[t] = (f32x4){0.f, 0.f, 0.f, 0.f};
#pragma unroll
    for (int t = 0; t < 8; ++t)
#pragma unroll
      for (int q = 0; q < 4; ++q) {
        bf16x8 b = fcWf[(t * 4 + q) * 64 + lane];
        acc[t] = __builtin_amdgcn_mfma_f32_16x16x32_bf16(Ah[q], b, acc[t], 0, 0, 0);
        acc[t] = __builtin_amdgcn_mfma_f32_16x16x32_bf16(Al[q], b, acc[t], 0, 0, 0);
      }
    // LayerNorm + L2 normalize + store
#pragma unroll
    for (int r = 0; r < 4; ++r) {
      float z[8];
      float s = 0.f;
#pragma unroll
      for (int t = 0; t < 8; ++t) { z[t] = acc[t][r] + fb[t]; s += z[t]; }
#pragma unroll
      for (int msk = 1; msk < 16; msk <<= 1) s += __shfl_xor(s, msk, 64);
      const float mu = s * (1.f / 128.f);
      float v = 0.f;
#pragma unroll
      for (int t = 0; t < 8; ++t) { z[t] -= mu; v += z[t] * z[t]; }
#pragma unroll
      for (int msk = 1; msk < 16; msk <<= 1) v += __shfl_xor(v, msk, 64);
      const float rstd = rsqrtf(v * (1.f / 128.f) + 1e-5f);
      float q2 = 0.f;
#pragma unroll
      for (int t = 0; t < 8; ++t) { z[t] = z[t] * rstd * g[t] + bb[t]; q2 += z[t] * z[t]; }
#pragma unroll
      for (int msk = 1; msk < 16; msk <<= 1) q2 += __shfl_xor(q2, msk, 64);
      const float rinv = 1.f / fmaxf(sqrtf(q2), 1e-12f);
      const int n = nb + lg * 4 + r;
      if (n < N) {
#pragma unroll
        for (int t = 0; t < 8; ++t) {
          float o = z[t] * rinv;
          xlocal[(size_t)n * 128 + lc + 16 * t] = o;
          cs[t] += o;
        }
      }
    }
  }
  // per-block column-sum partial (no global atomics)
#pragma unroll
  for (int t = 0; t < 8; ++t) {
    cs[t] += __shfl_xor(cs[t], 16, 64);
    cs[t] += __shfl_xor(cs[t], 32, 64);
  }
  if (lg == 0) {
#pragma unroll
    for (int t = 0; t < 8; ++t) colred[wid][lc + 16 * t] = cs[t];
  }
  __syncthreads();
  if (threadIdx.x < 128) {
    colpart[(size_t)blockIdx.x * 128 + threadIdx.x] =
        colred[0][threadIdx.x] + colred[1][threadIdx.x] +
        colred[2][threadIdx.x] + colred[3][threadIdx.x];
  }
}

// --- global attention vector ga[128]; reduces colpart[DBLK][128] ---
__global__ void k_gatt(const float* __restrict__ colpart, int nblk,
                       const float* __restrict__ gW, const float* __restrict__ gb,
                       float* __restrict__ ga, int N) {
  __shared__ float xg[128], r[128];
  int t = threadIdx.x;
  float s0 = 0.f;
  for (int b = 0; b < nblk; ++b) s0 += colpart[(size_t)b * 128 + t];
  xg[t] = s0 / (float)N;
  __syncthreads();
  float acc = gb[t];
  for (int k = 0; k < 128; ++k) acc += xg[k] * gW[t * 128 + k];
  acc = fmaxf(acc, 0.f);
  r[t] = acc;
  __syncthreads();
  float m = -1e30f;
  for (int k = 0; k < 128; ++k) m = fmaxf(m, r[k]);
  float s = 0.f;
  for (int k = 0; k < 128; ++k) s += __expf(r[k] - m);
  ga[t] = __expf(acc - m) / s;
}

// --- out *= ga (broadcast over rows) ---
__global__ void k_scale(float* __restrict__ out, const float* __restrict__ ga, int total4) {
  float4* o4 = (float4*)out;
  const float4* g4 = (const float4*)ga;
  for (int i = blockIdx.x * blockDim.x + threadIdx.x; i < total4; i += gridDim.x * blockDim.x) {
    float4 v = o4[i];
    float4 g = g4[i & 31];
    v.x *= g.x; v.y *= g.y; v.z *= g.z; v.w *= g.w;
    o4[i] = v;
  }
}

extern "C" void kernel_launch(void* const* d_in, const int* in_sizes, int n_in,
                              void* d_out, int out_size, void* d_ws, size_t ws_size,
                              hipStream_t stream) {
  const float* x    = (const float*)d_in[0];
  const void*  ei   = d_in[1];
  const float* Wc   = (const float*)d_in[2];
  const float* asrc = (const float*)d_in[3];
  const float* adst = (const float*)d_in[4];
  const float* bcv  = (const float*)d_in[5];
  const float* fcW  = (const float*)d_in[6];
  const float* fcb  = (const float*)d_in[7];
  const float* lng  = (const float*)d_in[8];
  const float* lnb  = (const float*)d_in[9];
  const float* gW   = (const float*)d_in[10];
  const float* gb   = (const float*)d_in[11];
  const int N = in_sizes[0] / 16;
  const int E = in_sizes[1] / 2;
  const int NB = (N + 255) >> 8;          // buckets of 256 nodes
  const int NCHUNK = (E + 8191) >> 13;    // 8192-edge partition chunks

  uint4*    xebf    = (uint4*)d_ws;                    // [N*4] 64B packed rows
  bf16x8*   fcWf    = (bf16x8*)(xebf + (size_t)N * 4); // [2048] frag-order bf16 fc_W
  float*    ald     = (float*)(fcWf + 2048);           // [N,8]
  int*      ecur    = (int*)(ald + (size_t)N * 8);     // [512]  (memset)
  float*    ga      = (float*)(ecur + 512);            // [128]
  int*      flag    = (int*)(ga + 128);                // [1]
  int*      off     = flag + 1;                        // [N]
  int*      deg     = off + N;                         // [N]
  float*    colpart = (float*)(deg + N);               // [DBLK*128]
  unsigned* pairs   = (unsigned*)(colpart + (size_t)DBLK * 128);  // [NB*CAP_E]
  int*      srcs    = (int*)(pairs + (size_t)NB * CAP_E);         // [NB*CAP_S]
  float*    out     = (float*)d_out;                   // doubles as xlocal

  hipMemsetAsync(ecur, 0, 512 * sizeof(int), stream);
  k_detect<<<1, 256, 0, stream>>>(ei, N, flag);
  k_wconv<<<8, 256, 0, stream>>>(fcW, fcWf);
  k_alpha<<<512, 256, 0, stream>>>(x, Wc, asrc, adst, xebf, ald, N);
  k_bfill2<<<NCHUNK, 256, 0, stream>>>(ei, flag, ecur, pairs, E);
  k_bcsr<<<NB, 256, 0, stream>>>(pairs, ecur, off, deg, srcs, N);
  k_xlocal<<<4096, 256, 0, stream>>>(xebf, off, deg, srcs, ald, Wc, bcv, out, N);
  k_dense2<<<DBLK, 256, 0, stream>>>(out, fcWf, fcb, lng, lnb, colpart, N);
  k_gatt<<<1, 128, 0, stream>>>(colpart, DBLK, gW, gb, ga, N);
  k_scale<<<2048, 256, 0, stream>>>(out, ga, N * 32);
}

// Round 14
// 269.912 us; speedup vs baseline: 1.8705x; 1.8705x over previous
//
#include <hip/hip_runtime.h>

#define CAP_E 5120              // edge slots per 256-node bucket (mean ~4090, +16 sigma)
#define CAP_S (CAP_E + 256)     // srcs slots per bucket (edges + self loops)
#define DBLK  1024              // k_dense2 grid

typedef __attribute__((ext_vector_type(8))) short bf16x8;
typedef __attribute__((ext_vector_type(4))) float f32x4;

__device__ __forceinline__ float lrelu(float v, float s) { return v >= 0.f ? v : s * v; }

__device__ __forceinline__ short bf16t(float f) {
  return (short)(__float_as_uint(f) >> 16);
}
__device__ __forceinline__ unsigned short bf16rn(float f) {  // round-to-nearest-even
  unsigned u = __float_as_uint(f);
  return (unsigned short)((u + 0x7fffu + ((u >> 16) & 1u)) >> 16);
}
__device__ __forceinline__ unsigned pk2(float a, float b) {
  return (unsigned)bf16rn(a) | ((unsigned)bf16rn(b) << 16);
}

// --- detect whether edge_index arrived as int64 or int32 ---
__global__ void k_detect(const void* __restrict__ ei, int N, int* __restrict__ flag) {
  __shared__ int bad;
  if (threadIdx.x == 0) bad = 0;
  __syncthreads();
  const long long* p = (const long long*)ei;
  int my = 0;
  for (int i = threadIdx.x; i < 1024; i += blockDim.x) {
    long long v = p[i];
    if (v < 0 || v >= (long long)N) my = 1;
  }
  if (my) atomicExch(&bad, 1);
  __syncthreads();
  if (threadIdx.x == 0) *flag = bad ? 0 : 1;  // 1 => int64
}

// --- fc_W -> frag-order bf16 (32 KB), done once; consumed via L1 by k_dense2 ---
__global__ void k_wconv(const float* __restrict__ fcW, bf16x8* __restrict__ fcWf) {
  int idx = blockIdx.x * 256 + threadIdx.x;
  if (idx >= 2048) return;
  int tq = idx >> 6, l = idx & 63;
  int t = tq >> 2, q = tq & 3;
  int col = (l & 15) + t * 16;
  int kb = q * 32 + (l >> 4) * 8;
  const float* wr = fcW + col * 128 + kb;
  bf16x8 v;
#pragma unroll
  for (int i = 0; i < 8; ++i) v[i] = bf16t(wr[i]);
  fcWf[idx] = v;
}

// --- per-node packed 64B row: xebf[n] = {16 bf16 x, 8 f32 als}; ald separate ---
__global__ void k_alpha(const float* __restrict__ x, const float* __restrict__ Wc,
                        const float* __restrict__ a_src, const float* __restrict__ a_dst,
                        uint4* __restrict__ xebf, float* __restrict__ ald, int N) {
  __shared__ float vs[128], vd[128];
  for (int t = threadIdx.x; t < 256; t += blockDim.x) {
    int h = (t & 127) >> 4, d = t & 15;
    const float* wrow = Wc + h * 256 + d * 16;
    const float* av = (t < 128 ? a_src : a_dst) + h * 16;
    float s = 0.f;
#pragma unroll
    for (int f = 0; f < 16; ++f) s += wrow[f] * av[f];
    if (t < 128) vs[h * 16 + d] = s; else vd[h * 16 + d] = s;
  }
  __syncthreads();
  for (int n = blockIdx.x * blockDim.x + threadIdx.x; n < N; n += gridDim.x * blockDim.x) {
    float xv[16];
    const float4* xr = (const float4*)(x + (size_t)n * 16);
    float4 q0 = xr[0], q1 = xr[1], q2 = xr[2], q3 = xr[3];
    xv[0]=q0.x; xv[1]=q0.y; xv[2]=q0.z; xv[3]=q0.w;
    xv[4]=q1.x; xv[5]=q1.y; xv[6]=q1.z; xv[7]=q1.w;
    xv[8]=q2.x; xv[9]=q2.y; xv[10]=q2.z; xv[11]=q2.w;
    xv[12]=q3.x; xv[13]=q3.y; xv[14]=q3.z; xv[15]=q3.w;
    float rs[8], rd[8];
#pragma unroll
    for (int h = 0; h < 8; ++h) {
      float s1 = 0.f, s2 = 0.f;
#pragma unroll
      for (int d = 0; d < 16; ++d) { s1 += xv[d] * vs[h * 16 + d]; s2 += xv[d] * vd[h * 16 + d]; }
      rs[h] = s1; rd[h] = s2;
    }
    uint4* po = xebf + (size_t)n * 4;
    uint4 wa, wb;
    wa.x = pk2(xv[0], xv[1]);  wa.y = pk2(xv[2], xv[3]);
    wa.z = pk2(xv[4], xv[5]);  wa.w = pk2(xv[6], xv[7]);
    wb.x = pk2(xv[8], xv[9]);  wb.y = pk2(xv[10], xv[11]);
    wb.z = pk2(xv[12], xv[13]); wb.w = pk2(xv[14], xv[15]);
    po[0] = wa; po[1] = wb;
    po[2] = *(const uint4*)(&rs[0]);
    po[3] = *(const uint4*)(&rs[4]);
    float4* pd = (float4*)(ald + (size_t)n * 8);
    pd[0] = make_float4(rd[0], rd[1], rd[2], rd[3]);
    pd[1] = make_float4(rd[4], rd[5], rd[6], rd[7]);
  }
}

// --- partition edges into fixed-capacity bucket regions (bucket = dst>>8);
//     one global atomic per (block,bucket); pairs = (src<<8)|(dst&255). ---
__global__ __launch_bounds__(256) void k_bfill2(const void* __restrict__ ei,
                                                const int* __restrict__ flag,
                                                int* __restrict__ ecur,
                                                unsigned* __restrict__ pairs, int E) {
  __shared__ int hist[512];
  __shared__ int gbase[512];
  const int is64 = *flag;
  const int base = blockIdx.x * 8192;
  for (int i = threadIdx.x; i < 512; i += 256) hist[i] = 0;
  __syncthreads();
  unsigned pk[32];
  int bs[32];  // (bucket<<13)|slot, or -1 if invalid
#pragma unroll
  for (int k = 0; k < 32; ++k) {
    const int i = base + k * 256 + threadIdx.x;
    bs[k] = -1;
    if (i < E) {
      int s, d;
      if (is64) { s = (int)((const long long*)ei)[i]; d = (int)((const long long*)ei)[(size_t)E + i]; }
      else      { s = ((const int*)ei)[i];            d = ((const int*)ei)[(size_t)E + i]; }
      const int b = d >> 8;
      const int slot = atomicAdd(&hist[b], 1);
      pk[k] = ((unsigned)s << 8) | (unsigned)(d & 255);
      bs[k] = (b << 13) | slot;
    }
  }
  __syncthreads();
  for (int i = threadIdx.x; i < 512; i += 256)
    if (hist[i] > 0) gbase[i] = i * CAP_E + atomicAdd(&ecur[i], hist[i]);
  __syncthreads();
#pragma unroll
  for (int k = 0; k < 32; ++k) {
    if (bs[k] >= 0) {
      const int b = bs[k] >> 13, slot = bs[k] & 8191;
      const int gi = gbase[b] + slot;
      if (gi < (b + 1) * CAP_E) pairs[gi] = pk[k];   // capacity guard (never triggers)
    }
  }
}

// --- per-bucket CSR: LDS histogram + scan; writes off[n], deg[n], srcs ---
__global__ __launch_bounds__(256) void k_bcsr(const unsigned* __restrict__ pairs,
                                              const int* __restrict__ ecur,
                                              int* __restrict__ off, int* __restrict__ deg,
                                              int* __restrict__ srcs, int N) {
  __shared__ int cnt[256], cur[256], wtot[4];
  const int b = blockIdx.x, t = threadIdx.x;
  const int nbase = b << 8;
  const int ncount = min(256, N - nbase);
  const int ebeg = b * CAP_E;
  const int eend = ebeg + min(ecur[b], CAP_E);
  const int ob = b * CAP_S;
  cnt[t] = (t < ncount) ? 1 : 0;  // self loop
  __syncthreads();
  for (int i = ebeg + t; i < eend; i += 256) atomicAdd(&cnt[pairs[i] & 255], 1);
  __syncthreads();
  const int wid = t >> 6, lane = t & 63;
  const int v = cnt[t];
  int inc = v;
#pragma unroll
  for (int d = 1; d < 64; d <<= 1) {
    int u = __shfl_up(inc, d, 64);
    if (lane >= d) inc += u;
  }
  if (lane == 63) wtot[wid] = inc;
  __syncthreads();
  int wb = 0;
  for (int w = 0; w < wid; ++w) wb += wtot[w];
  const int exc = wb + inc - v;
  if (t < ncount) {
    off[nbase + t] = ob + exc;
    deg[nbase + t] = v;
    srcs[ob + exc] = nbase + t;   // self loop first
    cur[t] = exc + 1;
  }
  __syncthreads();
  for (int i = ebeg + t; i < eend; i += 256) {
    unsigned e = pairs[i];
    int slot = atomicAdd(&cur[e & 255], 1);
    srcs[ob + slot] = (int)(e >> 8);
  }
}

// --- gather-aggregate + W_conv apply -> xlocal[N,128]. One wave per node,
//     8 edges/iter (es=lane>>3, h=lane&7); packed 64B rows (bf16 x + f32 als);
//     cross-node software pipeline. (round-9 structure, off/deg CSR) ---
__global__ __launch_bounds__(256) void k_xlocal(
    const uint4* __restrict__ xebf, const int* __restrict__ off,
    const int* __restrict__ deg, const int* __restrict__ srcs,
    const float* __restrict__ ald,
    const float* __restrict__ Wc, const float* __restrict__ b_conv,
    float* __restrict__ xlocal, int N) {
  __shared__ float W2t[2048];     // [d][h*16+f]
  __shared__ float myx[4][128];
  __shared__ float dsh[4][8];
  for (int i = threadIdx.x; i < 2048; i += blockDim.x) {
    int h = i >> 8, d = (i >> 4) & 15, f = i & 15;
    W2t[d * 128 + h * 16 + f] = Wc[i];
  }
  __syncthreads();
  const int wid = threadIdx.x >> 6, lane = threadIdx.x & 63;
  const int es = lane >> 3, h = lane & 7;
  const int c0 = lane, c1 = lane + 64;
  const int h0 = lane >> 4, h1 = h0 + 4;
  const float bc0 = b_conv[c0], bc1 = b_conv[c1];
  const int gw = blockIdx.x * 4 + wid, nwv = gridDim.x * 4;
  if (gw >= N) return;
  // prologue: node gw's extent + strip-0 row
  int b0 = off[gw], e0 = b0 + deg[gw];
  int s0 = srcs[min(b0 + es, e0 - 1)];
  uint4 xa = xebf[(size_t)s0 * 4], xb = xebf[(size_t)s0 * 4 + 1];
  float av = ((const float*)(xebf + (size_t)s0 * 4))[8 + h];
  for (int n = gw; n < N; n += nwv) {
    const int nn = n + nwv;
    int b1 = 0, e1 = 1;
    if (nn < N) { b1 = off[nn]; e1 = b1 + deg[nn]; }   // issue early
    const float aldh = ald[(size_t)n * 8 + h];
    float acc[16];
#pragma unroll
    for (int d = 0; d < 16; ++d) acc[d] = 0.f;
    float den = 0.f;
    for (int base = b0; base < e0; base += 8) {
      // prefetch next strip (clamped; last iteration's prefetch is discarded)
      int sn = srcs[min(base + 8 + es, e0 - 1)];
      const uint4* rn = xebf + (size_t)sn * 4;
      uint4 na = rn[0], nb = rn[1];
      float avn = ((const float*)rn)[8 + h];
      // compute current strip (decode bf16 pairs on the fly)
      float e = av + aldh;
      float w = ((base + es) < e0) ? __expf(e >= 0.f ? e : 0.2f * e) : 0.f;
      den += w;
      acc[0]  += w * __uint_as_float(xa.x << 16);
      acc[1]  += w * __uint_as_float(xa.x & 0xFFFF0000u);
      acc[2]  += w * __uint_as_float(xa.y << 16);
      acc[3]  += w * __uint_as_float(xa.y & 0xFFFF0000u);
      acc[4]  += w * __uint_as_float(xa.z << 16);
      acc[5]  += w * __uint_as_float(xa.z & 0xFFFF0000u);
      acc[6]  += w * __uint_as_float(xa.w << 16);
      acc[7]  += w * __uint_as_float(xa.w & 0xFFFF0000u);
      acc[8]  += w * __uint_as_float(xb.x << 16);
      acc[9]  += w * __uint_as_float(xb.x & 0xFFFF0000u);
      acc[10] += w * __uint_as_float(xb.y << 16);
      acc[11] += w * __uint_as_float(xb.y & 0xFFFF0000u);
      acc[12] += w * __uint_as_float(xb.z << 16);
      acc[13] += w * __uint_as_float(xb.z & 0xFFFF0000u);
      acc[14] += w * __uint_as_float(xb.w << 16);
      acc[15] += w * __uint_as_float(xb.w & 0xFFFF0000u);
      xa = na; xb = nb; av = avn;
    }
    // issue next node's strip-0 srcs (b1 already arrived)
    if (nn < N) s0 = srcs[min(b1 + es, e1 - 1)];
    // reduce across the 8 edge-slots (lanes h, h+8, ..., h+56)
#pragma unroll
    for (int m = 8; m < 64; m <<= 1) {
#pragma unroll
      for (int d = 0; d < 16; ++d) acc[d] += __shfl_xor(acc[d], m, 64);
      den += __shfl_xor(den, m, 64);
    }
    if (es == 0) {
#pragma unroll
      for (int d = 0; d < 16; ++d) myx[wid][h * 16 + d] = acc[d];
      dsh[wid][h] = den;
    }
    // issue next node's strip-0 row loads (hide under matvec+store)
    if (nn < N) {
      const uint4* r = xebf + (size_t)s0 * 4;
      xa = r[0]; xb = r[1];
      av = ((const float*)r)[8 + h];
    }
    // x_local[c] = (W_h . acc_h)/den_h + b_conv[c]
    const float rd0 = 1.f / dsh[wid][h0];
    const float rd1 = 1.f / dsh[wid][h1];
    float xl0 = 0.f, xl1 = 0.f;
#pragma unroll
    for (int d = 0; d < 16; ++d) {
      xl0 += myx[wid][h0 * 16 + d] * W2t[d * 128 + c0];
      xl1 += myx[wid][h1 * 16 + d] * W2t[d * 128 + c1];
    }
    xlocal[(size_t)n * 128 + c0] = xl0 * rd0 + bc0;
    xlocal[(size_t)n * 128 + c1] = xl1 * rd1 + bc1;
    b0 = b1; e0 = e1;
  }
}

// --- dense chain via MFMA. One wave per 16-node tile. B-frags read from global
//     frag-order bf16 fc_W (32 KB, L1-resident); LDS = x-stage only -> 4 blocks/CU.
//     colsum via per-block partials, TRANSPOSED layout colpart[c][DBLK]. ---
__global__ __launch_bounds__(256) void k_dense2(
    float* __restrict__ xlocal,   // in-place: rows read then overwritten
    const bf16x8* __restrict__ fcWf, const float* __restrict__ fcb,
    const float* __restrict__ lng, const float* __restrict__ lnb,
    float* __restrict__ colpart, int N) {
  __shared__ float xs[4][2112];   // per-wave 16x132 f32 stage (pad kills A-read conflicts)
  __shared__ float colred[4][128];
  const int wid = threadIdx.x >> 6, lane = threadIdx.x & 63;
  float* X = xs[wid];
  const int lg = lane >> 4;       // row-group (C) / k-group (A,B)
  const int lc = lane & 15;       // col-in-tile (C,B) / row (A)
  float fb[8], g[8], bb[8];
#pragma unroll
  for (int t = 0; t < 8; ++t) {
    int c = lc + t * 16;
    fb[t] = fcb[c]; g[t] = lng[c]; bb[t] = lnb[c];
  }
  float cs[8];
#pragma unroll
  for (int t = 0; t < 8; ++t) cs[t] = 0.f;
  const int ntiles = (N + 15) >> 4;
  const int srow = lane >> 2, sseg = lane & 3;
  for (int tile = blockIdx.x * 4 + wid; tile < ntiles; tile += gridDim.x * 4) {
    const int nb = tile * 16;
    // stage 16x128 tile of xlocal into LDS
#pragma unroll
    for (int j = 0; j < 8; ++j) {
      int n = min(nb + srow, N - 1);
      float4 v = *(const float4*)(xlocal + (size_t)n * 128 + (sseg + 4 * j) * 4);
      *(float4*)(X + srow * 132 + (sseg + 4 * j) * 4) = v;
    }
    // A fragments (hi/lo split), GEMM1
    bf16x8 Ah[4], Al[4];
#pragma unroll
    for (int q = 0; q < 4; ++q) {
      const float* p = X + lc * 132 + q * 32 + lg * 8;
      float a[8];
      *(float4*)(a) = *(const float4*)(p);
      *(float4*)(a + 4) = *(const float4*)(p + 4);
#pragma unroll
      for (int i = 0; i < 8; ++i) {
        unsigned u = __float_as_uint(a[i]);
        Ah[q][i] = (short)(u >> 16);
        Al[q][i] = bf16t(a[i] - __uint_as_float(u & 0xFFFF0000u));
      }
    }
    f32x4 acc[8];
#pragma unroll
    for (int t = 0; t < 8; ++t) acc[t] = (f32x4){0.f, 0.f, 0.f, 0.f};
#pragma unroll
    for (int t = 0; t < 8; ++t)
#pragma unroll
      for (int q = 0; q < 4; ++q) {
        bf16x8 b = fcWf[(t * 4 + q) * 64 + lane];
        acc[t] = __builtin_amdgcn_mfma_f32_16x16x32_bf16(Ah[q], b, acc[t], 0, 0, 0);
        acc[t] = __builtin_amdgcn_mfma_f32_16x16x32_bf16(Al[q], b, acc[t], 0, 0, 0);
      }
    // softmax over 128 cols per node-row; xl2 = lrelu(x*att, 0.2); write back to LDS
    float l1[8][4];
#pragma unroll
    for (int t = 0; t < 8; ++t)
#pragma unroll
      for (int r = 0; r < 4; ++r) {
        float z = acc[t][r] + fb[t];
        l1[t][r] = fmaxf(z, 0.01f * z);
      }
#pragma unroll
    for (int r = 0; r < 4; ++r) {
      float m = l1[0][r];
#pragma unroll
      for (int t = 1; t < 8; ++t) m = fmaxf(m, l1[t][r]);
#pragma unroll
      for (int msk = 1; msk < 16; msk <<= 1) m = fmaxf(m, __shfl_xor(m, msk, 64));
      float s = 0.f;
#pragma unroll
      for (int t = 0; t < 8; ++t) { l1[t][r] = __expf(l1[t][r] - m); s += l1[t][r]; }
#pragma unroll
      for (int msk = 1; msk < 16; msk <<= 1) s += __shfl_xor(s, msk, 64);
      float sinv = 1.f / s;
      const int row = lg * 4 + r;
#pragma unroll
      for (int t = 0; t < 8; ++t) {
        float xv = X[row * 132 + lc + 16 * t];
        float y = xv * (l1[t][r] * sinv);
        l1[t][r] = fmaxf(y, 0.2f * y);
      }
    }
#pragma unroll
    for (int t = 0; t < 8; ++t)
#pragma unroll
      for (int r = 0; r < 4; ++r)
        X[(lg * 4 + r) * 132 + lc + 16 * t] = l1[t][r];
    // GEMM2 on xl2
#pragma unroll
    for (int q = 0; q < 4; ++q) {
      const float* p = X + lc * 132 + q * 32 + lg * 8;
      float a[8];
      *(float4*)(a) = *(const float4*)(p);
      *(float4*)(a + 4) = *(const float4*)(p + 4);
#pragma unroll
      for (int i = 0; i < 8; ++i) {
        unsigned u = __float_as_uint(a[i]);
        Ah[q][i] = (short)(u >> 16);
        Al[q][i] = bf16t(a[i] - __uint_as_float(u & 0xFFFF0000u));
      }
    }
#pragma unroll
    for (int t = 0; t < 8; ++t) acc[t] = (f32x4){0.f, 0.f, 0.f, 0.f};
#pragma unroll
    for (int t = 0; t < 8; ++t)
#pragma unroll
      for (int q = 0; q < 4; ++q) {
        bf16x8 b = fcWf[(t * 4 + q) * 64 + lane];
        acc[t] = __builtin_amdgcn_mfma_f32_16x16x32_bf16(Ah[q], b, acc[t], 0, 0, 0);
        acc[t] = __builtin_amdgcn_mfma_f32_16x16x32_bf16(Al[q], b, acc[t], 0, 0, 0);
      }
    // LayerNorm + L2 normalize + store
#pragma unroll
    for (int r = 0; r < 4; ++r) {
      float z[8];
      float s = 0.f;
#pragma unroll
      for (int t = 0; t < 8; ++t) { z[t] = acc[t][r] + fb[t]; s += z[t]; }
#pragma unroll
      for (int msk = 1; msk < 16; msk <<= 1) s += __shfl_xor(s, msk, 64);
      const float mu = s * (1.f / 128.f);
      float v = 0.f;
#pragma unroll
      for (int t = 0; t < 8; ++t) { z[t] -= mu; v += z[t] * z[t]; }
#pragma unroll
      for (int msk = 1; msk < 16; msk <<= 1) v += __shfl_xor(v, msk, 64);
      const float rstd = rsqrtf(v * (1.f / 128.f) + 1e-5f);
      float q2 = 0.f;
#pragma unroll
      for (int t = 0; t < 8; ++t) { z[t] = z[t] * rstd * g[t] + bb[t]; q2 += z[t] * z[t]; }
#pragma unroll
      for (int msk = 1; msk < 16; msk <<= 1) q2 += __shfl_xor(q2, msk, 64);
      const float rinv = 1.f / fmaxf(sqrtf(q2), 1e-12f);
      const int n = nb + lg * 4 + r;
      if (n < N) {
#pragma unroll
        for (int t = 0; t < 8; ++t) {
          float o = z[t] * rinv;
          xlocal[(size_t)n * 128 + lc + 16 * t] = o;
          cs[t] += o;
        }
      }
    }
  }
  // per-block column-sum partial, transposed layout colpart[c*DBLK + bid]
#pragma unroll
  for (int t = 0; t < 8; ++t) {
    cs[t] += __shfl_xor(cs[t], 16, 64);
    cs[t] += __shfl_xor(cs[t], 32, 64);
  }
  if (lg == 0) {
#pragma unroll
    for (int t = 0; t < 8; ++t) colred[wid][lc + 16 * t] = cs[t];
  }
  __syncthreads();
  if (threadIdx.x < 128) {
    colpart[(size_t)threadIdx.x * DBLK + blockIdx.x] =
        colred[0][threadIdx.x] + colred[1][threadIdx.x] +
        colred[2][threadIdx.x] + colred[3][threadIdx.x];
  }
}

// --- reduce colpart[128][DBLK] -> colsum[128]; one block per channel ---
__global__ __launch_bounds__(256) void k_colred(const float* __restrict__ colpart,
                                                float* __restrict__ colsum) {
  const int c = blockIdx.x, t = threadIdx.x;
  float s = 0.f;
  for (int i = t; i < DBLK; i += 256) s += colpart[(size_t)c * DBLK + i];
#pragma unroll
  for (int m = 1; m < 64; m <<= 1) s += __shfl_xor(s, m, 64);
  __shared__ float ws[4];
  if ((t & 63) == 0) ws[t >> 6] = s;
  __syncthreads();
  if (t == 0) colsum[c] = ws[0] + ws[1] + ws[2] + ws[3];
}

// --- global attention vector ga[128] ---
__global__ void k_gatt(const float* __restrict__ colsum, const float* __restrict__ gW,
                       const float* __restrict__ gb, float* __restrict__ ga, int N) {
  __shared__ float xg[128], r[128];
  int t = threadIdx.x;
  xg[t] = colsum[t] / (float)N;
  __syncthreads();
  float acc = gb[t];
  for (int k = 0; k < 128; ++k) acc += xg[k] * gW[t * 128 + k];
  acc = fmaxf(acc, 0.f);
  r[t] = acc;
  __syncthreads();
  float m = -1e30f;
  for (int k = 0; k < 128; ++k) m = fmaxf(m, r[k]);
  float s = 0.f;
  for (int k = 0; k < 128; ++k) s += __expf(r[k] - m);
  ga[t] = __expf(acc - m) / s;
}

// --- out *= ga (broadcast over rows) ---
__global__ void k_scale(float* __restrict__ out, const float* __restrict__ ga, int total4) {
  float4* o4 = (float4*)out;
  const float4* g4 = (const float4*)ga;
  for (int i = blockIdx.x * blockDim.x + threadIdx.x; i < total4; i += gridDim.x * blockDim.x) {
    float4 v = o4[i];
    float4 g = g4[i & 31];
    v.x *= g.x; v.y *= g.y; v.z *= g.z; v.w *= g.w;
    o4[i] = v;
  }
}

extern "C" void kernel_launch(void* const* d_in, const int* in_sizes, int n_in,
                              void* d_out, int out_size, void* d_ws, size_t ws_size,
                              hipStream_t stream) {
  const float* x    = (const float*)d_in[0];
  const void*  ei   = d_in[1];
  const float* Wc   = (const float*)d_in[2];
  const float* asrc = (const float*)d_in[3];
  const float* adst = (const float*)d_in[4];
  const float* bcv  = (const float*)d_in[5];
  const float* fcW  = (const float*)d_in[6];
  const float* fcb  = (const float*)d_in[7];
  const float* lng  = (const float*)d_in[8];
  const float* lnb  = (const float*)d_in[9];
  const float* gW   = (const float*)d_in[10];
  const float* gb   = (const float*)d_in[11];
  const int N = in_sizes[0] / 16;
  const int E = in_sizes[1] / 2;
  const int NB = (N + 255) >> 8;          // buckets of 256 nodes
  const int NCHUNK = (E + 8191) >> 13;    // 8192-edge partition chunks

  uint4*    xebf    = (uint4*)d_ws;                    // [N*4] 64B packed rows
  bf16x8*   fcWf    = (bf16x8*)(xebf + (size_t)N * 4); // [2048] frag-order bf16 fc_W
  float*    ald     = (float*)(fcWf + 2048);           // [N,8]
  int*      ecur    = (int*)(ald + (size_t)N * 8);     // [512]  (memset)
  float*    ga      = (float*)(ecur + 512);            // [128]
  int*      flag    = (int*)(ga + 128);                // [1]
  int*      off     = flag + 1;                        // [N]
  int*      deg     = off + N;                         // [N]
  float*    colsum  = (float*)(deg + N);               // [128]
  float*    colpart = colsum + 128;                    // [128*DBLK]
  unsigned* pairs   = (unsigned*)(colpart + (size_t)128 * DBLK);  // [NB*CAP_E]
  int*      srcs    = (int*)(pairs + (size_t)NB * CAP_E);         // [NB*CAP_S]
  float*    out     = (float*)d_out;                   // doubles as xlocal

  hipMemsetAsync(ecur, 0, 512 * sizeof(int), stream);
  k_detect<<<1, 256, 0, stream>>>(ei, N, flag);
  k_wconv<<<8, 256, 0, stream>>>(fcW, fcWf);
  k_alpha<<<512, 256, 0, stream>>>(x, Wc, asrc, adst, xebf, ald, N);
  k_bfill2<<<NCHUNK, 256, 0, stream>>>(ei, flag, ecur, pairs, E);
  k_bcsr<<<NB, 256, 0, stream>>>(pairs, ecur, off, deg, srcs, N);
  k_xlocal<<<4096, 256, 0, stream>>>(xebf, off, deg, srcs, ald, Wc, bcv, out, N);
  k_dense2<<<DBLK, 256, 0, stream>>>(out, fcWf, fcb, lng, lnb, colpart, N);
  k_colred<<<128, 256, 0, stream>>>(colpart, colsum);
  k_gatt<<<1, 128, 0, stream>>>(colsum, gW, gb, ga, N);
  k_scale<<<2048, 256, 0, stream>>>(out, ga, N * 32);
}

// Round 15
// 218.520 us; speedup vs baseline: 2.3104x; 1.2352x over previous
//
#include <hip/hip_runtime.h>

#define CAP_E 5120              // edge slots per 256-node bucket (mean ~4090, +16 sigma)
#define CAP_S (CAP_E + 256)     // srcs slots per bucket (edges + self loops)
#define DBLK  1024              // k_dense2 grid

typedef __attribute__((ext_vector_type(8))) short bf16x8;
typedef __attribute__((ext_vector_type(4))) float f32x4;

__device__ __forceinline__ float lrelu(float v, float s) { return v >= 0.f ? v : s * v; }

__device__ __forceinline__ short bf16t(float f) {
  return (short)(__float_as_uint(f) >> 16);
}
__device__ __forceinline__ unsigned short bf16rn(float f) {  // round-to-nearest-even
  unsigned u = __float_as_uint(f);
  return (unsigned short)((u + 0x7fffu + ((u >> 16) & 1u)) >> 16);
}
__device__ __forceinline__ unsigned pk2(float a, float b) {
  return (unsigned)bf16rn(a) | ((unsigned)bf16rn(b) << 16);
}

// --- fused prep: detect int64 (block 0), fc_W->frag bf16 (blocks 1-8),
//     zero ecur (block 9), alpha/pack (all blocks, grid-stride) ---
__global__ __launch_bounds__(256) void k_prep(
    const float* __restrict__ x, const void* __restrict__ ei,
    const float* __restrict__ Wc,
    const float* __restrict__ a_src, const float* __restrict__ a_dst,
    const float* __restrict__ fcW,
    uint4* __restrict__ xebf, float* __restrict__ ald,
    bf16x8* __restrict__ fcWf, int* __restrict__ ecur,
    int* __restrict__ flag, int N, int E) {
  __shared__ float vs[128], vd[128];
  __shared__ int bad;
  const int t = threadIdx.x;
  if (blockIdx.x == 0) {
    if (t == 0) bad = 0;
    __syncthreads();
    const long long* p = (const long long*)ei;
    int my = 0;
    for (int i = t; i < 1024; i += 256) {
      long long v = p[i];
      if (v < 0 || v >= (long long)N) my = 1;
    }
    if (my) atomicExch(&bad, 1);
    __syncthreads();
    if (t == 0) *flag = bad ? 0 : 1;  // 1 => int64
  } else if (blockIdx.x <= 8) {
    const int idx = (blockIdx.x - 1) * 256 + t;
    int tq = idx >> 6, l = idx & 63;
    int tt = tq >> 2, q = tq & 3;
    int col = (l & 15) + tt * 16;
    int kb = q * 32 + (l >> 4) * 8;
    const float* wr = fcW + col * 128 + kb;
    bf16x8 v;
#pragma unroll
    for (int i = 0; i < 8; ++i) v[i] = bf16t(wr[i]);
    fcWf[idx] = v;
  } else if (blockIdx.x == 9) {
    if (t < 256) { ecur[t] = 0; ecur[t + 256] = 0; }
  }
  // alpha part (all blocks)
  for (int i = t; i < 256; i += 256) {
    int h = (i & 127) >> 4, d = i & 15;
    const float* wrow = Wc + h * 256 + d * 16;
    const float* av = (i < 128 ? a_src : a_dst) + h * 16;
    float s = 0.f;
#pragma unroll
    for (int f = 0; f < 16; ++f) s += wrow[f] * av[f];
    if (i < 128) vs[h * 16 + d] = s; else vd[h * 16 + d] = s;
  }
  __syncthreads();
  for (int n = blockIdx.x * blockDim.x + t; n < N; n += gridDim.x * blockDim.x) {
    float xv[16];
    const float4* xr = (const float4*)(x + (size_t)n * 16);
    float4 q0 = xr[0], q1 = xr[1], q2 = xr[2], q3 = xr[3];
    xv[0]=q0.x; xv[1]=q0.y; xv[2]=q0.z; xv[3]=q0.w;
    xv[4]=q1.x; xv[5]=q1.y; xv[6]=q1.z; xv[7]=q1.w;
    xv[8]=q2.x; xv[9]=q2.y; xv[10]=q2.z; xv[11]=q2.w;
    xv[12]=q3.x; xv[13]=q3.y; xv[14]=q3.z; xv[15]=q3.w;
    float rs[8], rd[8];
#pragma unroll
    for (int h = 0; h < 8; ++h) {
      float s1 = 0.f, s2 = 0.f;
#pragma unroll
      for (int d = 0; d < 16; ++d) { s1 += xv[d] * vs[h * 16 + d]; s2 += xv[d] * vd[h * 16 + d]; }
      rs[h] = s1; rd[h] = s2;
    }
    uint4* po = xebf + (size_t)n * 4;
    uint4 wa, wb;
    wa.x = pk2(xv[0], xv[1]);  wa.y = pk2(xv[2], xv[3]);
    wa.z = pk2(xv[4], xv[5]);  wa.w = pk2(xv[6], xv[7]);
    wb.x = pk2(xv[8], xv[9]);  wb.y = pk2(xv[10], xv[11]);
    wb.z = pk2(xv[12], xv[13]); wb.w = pk2(xv[14], xv[15]);
    po[0] = wa; po[1] = wb;
    po[2] = *(const uint4*)(&rs[0]);
    po[3] = *(const uint4*)(&rs[4]);
    float4* pd = (float4*)(ald + (size_t)n * 8);
    pd[0] = make_float4(rd[0], rd[1], rd[2], rd[3]);
    pd[1] = make_float4(rd[4], rd[5], rd[6], rd[7]);
  }
}

// --- partition edges into fixed-capacity bucket regions (bucket = dst>>8);
//     one global atomic per (block,bucket); pairs = (src<<8)|(dst&255). ---
__global__ __launch_bounds__(256) void k_bfill2(const void* __restrict__ ei,
                                                const int* __restrict__ flag,
                                                int* __restrict__ ecur,
                                                unsigned* __restrict__ pairs, int E) {
  __shared__ int hist[512];
  __shared__ int gbase[512];
  const int is64 = *flag;
  const int base = blockIdx.x * 8192;
  for (int i = threadIdx.x; i < 512; i += 256) hist[i] = 0;
  __syncthreads();
  unsigned pk[32];
  int bs[32];  // (bucket<<13)|slot, or -1 if invalid
#pragma unroll
  for (int k = 0; k < 32; ++k) {
    const int i = base + k * 256 + threadIdx.x;
    bs[k] = -1;
    if (i < E) {
      int s, d;
      if (is64) { s = (int)((const long long*)ei)[i]; d = (int)((const long long*)ei)[(size_t)E + i]; }
      else      { s = ((const int*)ei)[i];            d = ((const int*)ei)[(size_t)E + i]; }
      const int b = d >> 8;
      const int slot = atomicAdd(&hist[b], 1);
      pk[k] = ((unsigned)s << 8) | (unsigned)(d & 255);
      bs[k] = (b << 13) | slot;
    }
  }
  __syncthreads();
  for (int i = threadIdx.x; i < 512; i += 256)
    if (hist[i] > 0) gbase[i] = i * CAP_E + atomicAdd(&ecur[i], hist[i]);
  __syncthreads();
#pragma unroll
  for (int k = 0; k < 32; ++k) {
    if (bs[k] >= 0) {
      const int b = bs[k] >> 13, slot = bs[k] & 8191;
      const int gi = gbase[b] + slot;
      if (gi < (b + 1) * CAP_E) pairs[gi] = pk[k];   // capacity guard (never triggers)
    }
  }
}

// --- per-bucket CSR: LDS histogram + scan; writes off[n], deg[n], srcs ---
__global__ __launch_bounds__(256) void k_bcsr(const unsigned* __restrict__ pairs,
                                              const int* __restrict__ ecur,
                                              int* __restrict__ off, int* __restrict__ deg,
                                              int* __restrict__ srcs, int N) {
  __shared__ int cnt[256], cur[256], wtot[4];
  const int b = blockIdx.x, t = threadIdx.x;
  const int nbase = b << 8;
  const int ncount = min(256, N - nbase);
  const int ebeg = b * CAP_E;
  const int eend = ebeg + min(ecur[b], CAP_E);
  const int ob = b * CAP_S;
  cnt[t] = (t < ncount) ? 1 : 0;  // self loop
  __syncthreads();
  for (int i = ebeg + t; i < eend; i += 256) atomicAdd(&cnt[pairs[i] & 255], 1);
  __syncthreads();
  const int wid = t >> 6, lane = t & 63;
  const int v = cnt[t];
  int inc = v;
#pragma unroll
  for (int d = 1; d < 64; d <<= 1) {
    int u = __shfl_up(inc, d, 64);
    if (lane >= d) inc += u;
  }
  if (lane == 63) wtot[wid] = inc;
  __syncthreads();
  int wb = 0;
  for (int w = 0; w < wid; ++w) wb += wtot[w];
  const int exc = wb + inc - v;
  if (t < ncount) {
    off[nbase + t] = ob + exc;
    deg[nbase + t] = v;
    srcs[ob + exc] = nbase + t;   // self loop first
    cur[t] = exc + 1;
  }
  __syncthreads();
  for (int i = ebeg + t; i < eend; i += 256) {
    unsigned e = pairs[i];
    int slot = atomicAdd(&cur[e & 255], 1);
    srcs[ob + slot] = (int)(e >> 8);
  }
}

// --- gather-aggregate + W_conv apply -> xlocal[N,128]. One wave per node,
//     8 edges/iter (es=lane>>3, h=lane&7); packed 64B rows (bf16 x + f32 als);
//     cross-node software pipeline. (round-9 structure, off/deg CSR) ---
__global__ __launch_bounds__(256) void k_xlocal(
    const uint4* __restrict__ xebf, const int* __restrict__ off,
    const int* __restrict__ deg, const int* __restrict__ srcs,
    const float* __restrict__ ald,
    const float* __restrict__ Wc, const float* __restrict__ b_conv,
    float* __restrict__ xlocal, int N) {
  __shared__ float W2t[2048];     // [d][h*16+f]
  __shared__ float myx[4][128];
  __shared__ float dsh[4][8];
  for (int i = threadIdx.x; i < 2048; i += blockDim.x) {
    int h = i >> 8, d = (i >> 4) & 15, f = i & 15;
    W2t[d * 128 + h * 16 + f] = Wc[i];
  }
  __syncthreads();
  const int wid = threadIdx.x >> 6, lane = threadIdx.x & 63;
  const int es = lane >> 3, h = lane & 7;
  const int c0 = lane, c1 = lane + 64;
  const int h0 = lane >> 4, h1 = h0 + 4;
  const float bc0 = b_conv[c0], bc1 = b_conv[c1];
  const int gw = blockIdx.x * 4 + wid, nwv = gridDim.x * 4;
  if (gw >= N) return;
  // prologue: node gw's extent + strip-0 row
  int b0 = off[gw], e0 = b0 + deg[gw];
  int s0 = srcs[min(b0 + es, e0 - 1)];
  uint4 xa = xebf[(size_t)s0 * 4], xb = xebf[(size_t)s0 * 4 + 1];
  float av = ((const float*)(xebf + (size_t)s0 * 4))[8 + h];
  for (int n = gw; n < N; n += nwv) {
    const int nn = n + nwv;
    int b1 = 0, e1 = 1;
    if (nn < N) { b1 = off[nn]; e1 = b1 + deg[nn]; }   // issue early
    const float aldh = ald[(size_t)n * 8 + h];
    float acc[16];
#pragma unroll
    for (int d = 0; d < 16; ++d) acc[d] = 0.f;
    float den = 0.f;
    for (int base = b0; base < e0; base += 8) {
      // prefetch next strip (clamped; last iteration's prefetch is discarded)
      int sn = srcs[min(base + 8 + es, e0 - 1)];
      const uint4* rn = xebf + (size_t)sn * 4;
      uint4 na = rn[0], nb = rn[1];
      float avn = ((const float*)rn)[8 + h];
      // compute current strip (decode bf16 pairs on the fly)
      float e = av + aldh;
      float w = ((base + es) < e0) ? __expf(e >= 0.f ? e : 0.2f * e) : 0.f;
      den += w;
      acc[0]  += w * __uint_as_float(xa.x << 16);
      acc[1]  += w * __uint_as_float(xa.x & 0xFFFF0000u);
      acc[2]  += w * __uint_as_float(xa.y << 16);
      acc[3]  += w * __uint_as_float(xa.y & 0xFFFF0000u);
      acc[4]  += w * __uint_as_float(xa.z << 16);
      acc[5]  += w * __uint_as_float(xa.z & 0xFFFF0000u);
      acc[6]  += w * __uint_as_float(xa.w << 16);
      acc[7]  += w * __uint_as_float(xa.w & 0xFFFF0000u);
      acc[8]  += w * __uint_as_float(xb.x << 16);
      acc[9]  += w * __uint_as_float(xb.x & 0xFFFF0000u);
      acc[10] += w * __uint_as_float(xb.y << 16);
      acc[11] += w * __uint_as_float(xb.y & 0xFFFF0000u);
      acc[12] += w * __uint_as_float(xb.z << 16);
      acc[13] += w * __uint_as_float(xb.z & 0xFFFF0000u);
      acc[14] += w * __uint_as_float(xb.w << 16);
      acc[15] += w * __uint_as_float(xb.w & 0xFFFF0000u);
      xa = na; xb = nb; av = avn;
    }
    // issue next node's strip-0 srcs (b1 already arrived)
    if (nn < N) s0 = srcs[min(b1 + es, e1 - 1)];
    // reduce across the 8 edge-slots (lanes h, h+8, ..., h+56)
#pragma unroll
    for (int m = 8; m < 64; m <<= 1) {
#pragma unroll
      for (int d = 0; d < 16; ++d) acc[d] += __shfl_xor(acc[d], m, 64);
      den += __shfl_xor(den, m, 64);
    }
    if (es == 0) {
#pragma unroll
      for (int d = 0; d < 16; ++d) myx[wid][h * 16 + d] = acc[d];
      dsh[wid][h] = den;
    }
    // issue next node's strip-0 row loads (hide under matvec+store)
    if (nn < N) {
      const uint4* r = xebf + (size_t)s0 * 4;
      xa = r[0]; xb = r[1];
      av = ((const float*)r)[8 + h];
    }
    // x_local[c] = (W_h . acc_h)/den_h + b_conv[c]
    const float rd0 = 1.f / dsh[wid][h0];
    const float rd1 = 1.f / dsh[wid][h1];
    float xl0 = 0.f, xl1 = 0.f;
#pragma unroll
    for (int d = 0; d < 16; ++d) {
      xl0 += myx[wid][h0 * 16 + d] * W2t[d * 128 + c0];
      xl1 += myx[wid][h1 * 16 + d] * W2t[d * 128 + c1];
    }
    xlocal[(size_t)n * 128 + c0] = xl0 * rd0 + bc0;
    xlocal[(size_t)n * 128 + c1] = xl1 * rd1 + bc1;
    b0 = b1; e0 = e1;
  }
}

// --- dense chain via MFMA. One wave per 16-node tile. B-frags read from global
//     frag-order bf16 fc_W (32 KB, L1-resident); LDS = x-stage only -> 4 blocks/CU.
//     colsum via per-block partials, TRANSPOSED layout colpart[c][DBLK]. ---
__global__ __launch_bounds__(256) void k_dense2(
    float* __restrict__ xlocal,   // in-place: rows read then overwritten
    const bf16x8* __restrict__ fcWf, const float* __restrict__ fcb,
    const float* __restrict__ lng, const float* __restrict__ lnb,
    float* __restrict__ colpart, int N) {
  __shared__ float xs[4][2112];   // per-wave 16x132 f32 stage (pad kills A-read conflicts)
  __shared__ float colred[4][128];
  const int wid = threadIdx.x >> 6, lane = threadIdx.x & 63;
  float* X = xs[wid];
  const int lg = lane >> 4;       // row-group (C) / k-group (A,B)
  const int lc = lane & 15;       // col-in-tile (C,B) / row (A)
  float fb[8], g[8], bb[8];
#pragma unroll
  for (int t = 0; t < 8; ++t) {
    int c = lc + t * 16;
    fb[t] = fcb[c]; g[t] = lng[c]; bb[t] = lnb[c];
  }
  float cs[8];
#pragma unroll
  for (int t = 0; t < 8; ++t) cs[t] = 0.f;
  const int ntiles = (N + 15) >> 4;
  const int srow = lane >> 2, sseg = lane & 3;
  for (int tile = blockIdx.x * 4 + wid; tile < ntiles; tile += gridDim.x * 4) {
    const int nb = tile * 16;
    // stage 16x128 tile of xlocal into LDS
#pragma unroll
    for (int j = 0; j < 8; ++j) {
      int n = min(nb + srow, N - 1);
      float4 v = *(const float4*)(xlocal + (size_t)n * 128 + (sseg + 4 * j) * 4);
      *(float4*)(X + srow * 132 + (sseg + 4 * j) * 4) = v;
    }
    // A fragments (hi/lo split), GEMM1
    bf16x8 Ah[4], Al[4];
#pragma unroll
    for (int q = 0; q < 4; ++q) {
      const float* p = X + lc * 132 + q * 32 + lg * 8;
      float a[8];
      *(float4*)(a) = *(const float4*)(p);
      *(float4*)(a + 4) = *(const float4*)(p + 4);
#pragma unroll
      for (int i = 0; i < 8; ++i) {
        unsigned u = __float_as_uint(a[i]);
        Ah[q][i] = (short)(u >> 16);
        Al[q][i] = bf16t(a[i] - __uint_as_float(u & 0xFFFF0000u));
      }
    }
    f32x4 acc[8];
#pragma unroll
    for (int t = 0; t < 8; ++t) acc[t] = (f32x4){0.f, 0.f, 0.f, 0.f};
#pragma unroll
    for (int t = 0; t < 8; ++t)
#pragma unroll
      for (int q = 0; q < 4; ++q) {
        bf16x8 b = fcWf[(t * 4 + q) * 64 + lane];
        acc[t] = __builtin_amdgcn_mfma_f32_16x16x32_bf16(Ah[q], b, acc[t], 0, 0, 0);
        acc[t] = __builtin_amdgcn_mfma_f32_16x16x32_bf16(Al[q], b, acc[t], 0, 0, 0);
      }
    // softmax over 128 cols per node-row; xl2 = lrelu(x*att, 0.2); write back to LDS
    float l1[8][4];
#pragma unroll
    for (int t = 0; t < 8; ++t)
#pragma unroll
      for (int r = 0; r < 4; ++r) {
        float z = acc[t][r] + fb[t];
        l1[t][r] = fmaxf(z, 0.01f * z);
      }
#pragma unroll
    for (int r = 0; r < 4; ++r) {
      float m = l1[0][r];
#pragma unroll
      for (int t = 1; t < 8; ++t) m = fmaxf(m, l1[t][r]);
#pragma unroll
      for (int msk = 1; msk < 16; msk <<= 1) m = fmaxf(m, __shfl_xor(m, msk, 64));
      float s = 0.f;
#pragma unroll
      for (int t = 0; t < 8; ++t) { l1[t][r] = __expf(l1[t][r] - m); s += l1[t][r]; }
#pragma unroll
      for (int msk = 1; msk < 16; msk <<= 1) s += __shfl_xor(s, msk, 64);
      float sinv = 1.f / s;
      const int row = lg * 4 + r;
#pragma unroll
      for (int t = 0; t < 8; ++t) {
        float xv = X[row * 132 + lc + 16 * t];
        float y = xv * (l1[t][r] * sinv);
        l1[t][r] = fmaxf(y, 0.2f * y);
      }
    }
#pragma unroll
    for (int t = 0; t < 8; ++t)
#pragma unroll
      for (int r = 0; r < 4; ++r)
        X[(lg * 4 + r) * 132 + lc + 16 * t] = l1[t][r];
    // GEMM2 on xl2
#pragma unroll
    for (int q = 0; q < 4; ++q) {
      const float* p = X + lc * 132 + q * 32 + lg * 8;
      float a[8];
      *(float4*)(a) = *(const float4*)(p);
      *(float4*)(a + 4) = *(const float4*)(p + 4);
#pragma unroll
      for (int i = 0; i < 8; ++i) {
        unsigned u = __float_as_uint(a[i]);
        Ah[q][i] = (short)(u >> 16);
        Al[q][i] = bf16t(a[i] - __uint_as_float(u & 0xFFFF0000u));
      }
    }
#pragma unroll
    for (int t = 0; t < 8; ++t) acc[t] = (f32x4){0.f, 0.f, 0.f, 0.f};
#pragma unroll
    for (int t = 0; t < 8; ++t)
#pragma unroll
      for (int q = 0; q < 4; ++q) {
        bf16x8 b = fcWf[(t * 4 + q) * 64 + lane];
        acc[t] = __builtin_amdgcn_mfma_f32_16x16x32_bf16(Ah[q], b, acc[t], 0, 0, 0);
        acc[t] = __builtin_amdgcn_mfma_f32_16x16x32_bf16(Al[q], b, acc[t], 0, 0, 0);
      }
    // LayerNorm + L2 normalize + store
#pragma unroll
    for (int r = 0; r < 4; ++r) {
      float z[8];
      float s = 0.f;
#pragma unroll
      for (int t = 0; t < 8; ++t) { z[t] = acc[t][r] + fb[t]; s += z[t]; }
#pragma unroll
      for (int msk = 1; msk < 16; msk <<= 1) s += __shfl_xor(s, msk, 64);
      const float mu = s * (1.f / 128.f);
      float v = 0.f;
#pragma unroll
      for (int t = 0; t < 8; ++t) { z[t] -= mu; v += z[t] * z[t]; }
#pragma unroll
      for (int msk = 1; msk < 16; msk <<= 1) v += __shfl_xor(v, msk, 64);
      const float rstd = rsqrtf(v * (1.f / 128.f) + 1e-5f);
      float q2 = 0.f;
#pragma unroll
      for (int t = 0; t < 8; ++t) { z[t] = z[t] * rstd * g[t] + bb[t]; q2 += z[t] * z[t]; }
#pragma unroll
      for (int msk = 1; msk < 16; msk <<= 1) q2 += __shfl_xor(q2, msk, 64);
      const float rinv = 1.f / fmaxf(sqrtf(q2), 1e-12f);
      const int n = nb + lg * 4 + r;
      if (n < N) {
#pragma unroll
        for (int t = 0; t < 8; ++t) {
          float o = z[t] * rinv;
          xlocal[(size_t)n * 128 + lc + 16 * t] = o;
          cs[t] += o;
        }
      }
    }
  }
  // per-block column-sum partial, transposed layout colpart[c*DBLK + bid]
#pragma unroll
  for (int t = 0; t < 8; ++t) {
    cs[t] += __shfl_xor(cs[t], 16, 64);
    cs[t] += __shfl_xor(cs[t], 32, 64);
  }
  if (lg == 0) {
#pragma unroll
    for (int t = 0; t < 8; ++t) colred[wid][lc + 16 * t] = cs[t];
  }
  __syncthreads();
  if (threadIdx.x < 128) {
    colpart[(size_t)threadIdx.x * DBLK + blockIdx.x] =
        colred[0][threadIdx.x] + colred[1][threadIdx.x] +
        colred[2][threadIdx.x] + colred[3][threadIdx.x];
  }
}

// --- reduce colpart[128][DBLK] -> colsum[128]; one block per channel ---
__global__ __launch_bounds__(256) void k_colred(const float* __restrict__ colpart,
                                                float* __restrict__ colsum) {
  const int c = blockIdx.x, t = threadIdx.x;
  float s = 0.f;
  for (int i = t; i < DBLK; i += 256) s += colpart[(size_t)c * DBLK + i];
#pragma unroll
  for (int m = 1; m < 64; m <<= 1) s += __shfl_xor(s, m, 64);
  __shared__ float ws[4];
  if ((t & 63) == 0) ws[t >> 6] = s;
  __syncthreads();
  if (t == 0) colsum[c] = ws[0] + ws[1] + ws[2] + ws[3];
}

// --- global attention vector ga[128] ---
__global__ void k_gatt(const float* __restrict__ colsum, const float* __restrict__ gW,
                       const float* __restrict__ gb, float* __restrict__ ga, int N) {
  __shared__ float xg[128], r[128];
  int t = threadIdx.x;
  xg[t] = colsum[t] / (float)N;
  __syncthreads();
  float acc = gb[t];
  for (int k = 0; k < 128; ++k) acc += xg[k] * gW[t * 128 + k];
  acc = fmaxf(acc, 0.f);
  r[t] = acc;
  __syncthreads();
  float m = -1e30f;
  for (int k = 0; k < 128; ++k) m = fmaxf(m, r[k]);
  float s = 0.f;
  for (int k = 0; k < 128; ++k) s += __expf(r[k] - m);
  ga[t] = __expf(acc - m) / s;
}

// --- out *= ga (broadcast over rows) ---
__global__ void k_scale(float* __restrict__ out, const float* __restrict__ ga, int total4) {
  float4* o4 = (float4*)out;
  const float4* g4 = (const float4*)ga;
  for (int i = blockIdx.x * blockDim.x + threadIdx.x; i < total4; i += gridDim.x * blockDim.x) {
    float4 v = o4[i];
    float4 g = g4[i & 31];
    v.x *= g.x; v.y *= g.y; v.z *= g.z; v.w *= g.w;
    o4[i] = v;
  }
}

extern "C" void kernel_launch(void* const* d_in, const int* in_sizes, int n_in,
                              void* d_out, int out_size, void* d_ws, size_t ws_size,
                              hipStream_t stream) {
  const float* x    = (const float*)d_in[0];
  const void*  ei   = d_in[1];
  const float* Wc   = (const float*)d_in[2];
  const float* asrc = (const float*)d_in[3];
  const float* adst = (const float*)d_in[4];
  const float* bcv  = (const float*)d_in[5];
  const float* fcW  = (const float*)d_in[6];
  const float* fcb  = (const float*)d_in[7];
  const float* lng  = (const float*)d_in[8];
  const float* lnb  = (const float*)d_in[9];
  const float* gW   = (const float*)d_in[10];
  const float* gb   = (const float*)d_in[11];
  const int N = in_sizes[0] / 16;
  const int E = in_sizes[1] / 2;
  const int NB = (N + 255) >> 8;          // buckets of 256 nodes
  const int NCHUNK = (E + 8191) >> 13;    // 8192-edge partition chunks

  uint4*    xebf    = (uint4*)d_ws;                    // [N*4] 64B packed rows
  bf16x8*   fcWf    = (bf16x8*)(xebf + (size_t)N * 4); // [2048] frag-order bf16 fc_W
  float*    ald     = (float*)(fcWf + 2048);           // [N,8]
  int*      ecur    = (int*)(ald + (size_t)N * 8);     // [512] (zeroed in k_prep)
  float*    ga      = (float*)(ecur + 512);            // [128]
  int*      flag    = (int*)(ga + 128);                // [1]
  int*      off     = flag + 1;                        // [N]
  int*      deg     = off + N;                         // [N]
  float*    colsum  = (float*)(deg + N);               // [128]
  float*    colpart = colsum + 128;                    // [128*DBLK]
  unsigned* pairs   = (unsigned*)(colpart + (size_t)128 * DBLK);  // [NB*CAP_E]
  int*      srcs    = (int*)(pairs + (size_t)NB * CAP_E);         // [NB*CAP_S]
  float*    out     = (float*)d_out;                   // doubles as xlocal

  k_prep<<<512, 256, 0, stream>>>(x, ei, Wc, asrc, adst, fcW, xebf, ald, fcWf,
                                  ecur, flag, N, E);
  k_bfill2<<<NCHUNK, 256, 0, stream>>>(ei, flag, ecur, pairs, E);
  k_bcsr<<<NB, 256, 0, stream>>>(pairs, ecur, off, deg, srcs, N);
  k_xlocal<<<2048, 256, 0, stream>>>(xebf, off, deg, srcs, ald, Wc, bcv, out, N);
  k_dense2<<<DBLK, 256, 0, stream>>>(out, fcWf, fcb, lng, lnb, colpart, N);
  k_colred<<<128, 256, 0, stream>>>(colpart, colsum);
  k_gatt<<<1, 128, 0, stream>>>(colsum, gW, gb, ga, N);
  k_scale<<<2048, 256, 0, stream>>>(out, ga, N * 32);
}